// Round 1
// baseline (6216.202 us; speedup 1.0000x reference)
//
#include <hip/hip_runtime.h>
#include <hip/hip_cooperative_groups.h>
#include <cstddef>

namespace cg = cooperative_groups;

#define B_ 32
#define T_ENC_ 64
#define T_DEC_ 32
#define ENC_H_ 512
#define DEC_H_ 1024
#define V_E_ 32000

typedef __bf16 bf16x8_t __attribute__((ext_vector_type(8)));
typedef float f32x4_t __attribute__((ext_vector_type(4)));

__device__ __forceinline__ float sigm(float x) { return 1.f / (1.f + expf(-x)); }

__device__ __forceinline__ unsigned short f2bf(float f) {
  union { float f; unsigned u; } v; v.f = f;
  unsigned u = v.u;
  unsigned r = (u + 0x7fffu + ((u >> 16) & 1u)) >> 16;
  return (unsigned short)r;
}

// ---------------- Wc fp32 -> bf16 convert ----------------
__global__ __launch_bounds__(256) void conv_bf16(const float* __restrict__ src,
                                                 unsigned short* __restrict__ dst, int n8) {
  int i = blockIdx.x * 256 + threadIdx.x;
  if (i >= n8) return;
  float4 v0 = *(const float4*)(src + (size_t)i * 8);
  float4 v1 = *(const float4*)(src + (size_t)i * 8 + 4);
  union { unsigned short u[8]; uint4 v; } o;
  o.u[0] = f2bf(v0.x); o.u[1] = f2bf(v0.y); o.u[2] = f2bf(v0.z); o.u[3] = f2bf(v0.w);
  o.u[4] = f2bf(v1.x); o.u[5] = f2bf(v1.y); o.u[6] = f2bf(v1.z); o.u[7] = f2bf(v1.w);
  *(uint4*)(dst + (size_t)i * 8) = o.v;
}

// ---------------- fp32 tiled GEMM with embedding-gather A ----------------
__global__ __launch_bounds__(256) void gemm_gather(
    const float* __restrict__ emb, const int* __restrict__ idx,
    const int* __restrict__ lens, const float* __restrict__ W, int ldw,
    const float* __restrict__ bias1, const float* __restrict__ bias2,
    float* __restrict__ out, int N, int mode) {
  __shared__ __align__(16) float s_at[16][68];
  __shared__ __align__(16) float s_bt[16][68];
  __shared__ int gidx[64];
  const int tid = threadIdx.x;
  const int tx = tid & 15, ty = tid >> 4;
  const int n0 = blockIdx.x * 64, m0 = blockIdx.y * 64;

  if (tid < 64) {
    int m = m0 + tid;
    int t = m >> 5, b = m & 31;
    int gi;
    if (mode == 0) gi = idx[b * 64 + t];
    else if (mode == 1) {
      int len = lens[b];
      int tt = (t < len) ? (len - 1 - t) : t;
      gi = idx[b * 64 + tt];
    } else gi = idx[b * 32 + t];
    gidx[tid] = gi;
  }
  __syncthreads();

  float acc[4][4] = {};
  const int r = tid >> 2, c4 = tid & 3;
  for (int kc = 0; kc < 512; kc += 16) {
    float4 av = *(const float4*)(emb + (size_t)gidx[r] * 512 + kc + c4 * 4);
    float4 bv = *(const float4*)(W + (size_t)(n0 + r) * ldw + kc + c4 * 4);
    s_at[c4 * 4 + 0][r] = av.x; s_at[c4 * 4 + 1][r] = av.y;
    s_at[c4 * 4 + 2][r] = av.z; s_at[c4 * 4 + 3][r] = av.w;
    s_bt[c4 * 4 + 0][r] = bv.x; s_bt[c4 * 4 + 1][r] = bv.y;
    s_bt[c4 * 4 + 2][r] = bv.z; s_bt[c4 * 4 + 3][r] = bv.w;
    __syncthreads();
#pragma unroll
    for (int kk = 0; kk < 16; ++kk) {
      float4 a4 = *(const float4*)&s_at[kk][ty * 4];
      float4 b4 = *(const float4*)&s_bt[kk][tx * 4];
      float avv[4] = {a4.x, a4.y, a4.z, a4.w};
      float bvv[4] = {b4.x, b4.y, b4.z, b4.w};
#pragma unroll
      for (int i = 0; i < 4; ++i)
#pragma unroll
        for (int j = 0; j < 4; ++j)
          acc[i][j] = fmaf(avv[i], bvv[j], acc[i][j]);
    }
    __syncthreads();
  }
#pragma unroll
  for (int i = 0; i < 4; ++i) {
    int m = m0 + ty * 4 + i;
#pragma unroll
    for (int j = 0; j < 4; ++j) {
      int n = n0 + tx * 4 + j;
      float v = acc[i][j] + bias1[n] + (bias2 ? bias2[n] : 0.f);
      out[(size_t)m * N + n] = v;
    }
  }
}

// ---------------- cooperative kernel: recurrences ----------------
struct CoopParams {
  const int* lens;
  const float* Wa; const float* ba; const float* va;
  const float* Wi; const float* bh;
  const float* W_hh_f; const float* W_hh_b;
  const float* xg_f; const float* xg_b; const float* gi_pre;
  float* h_f_out; float* h_b_rev; float* enc_out; float* attE;
  float* h_cur; float* state; float* context;
  unsigned short* a_cls;
};

__global__ __launch_bounds__(256) void coop_kernel(CoopParams p) {
  cg::grid_group grid = cg::this_grid();
  const int tid = threadIdx.x;
  const int blk = blockIdx.x;

  // weight stage: union of encoder [16][129] f4 (2064) and decoder [12][257] f4 (3084)
  __shared__ __align__(16) float4 swu[3084];
  __shared__ float gates_lds[32][4][4];
  __shared__ float sh_qp[8][33];
  __shared__ float sh_q[8];
  __shared__ float sh_al[64];

  // ===== encoder bi-LSTM: weights LDS-resident, 1 grid.sync/step (R1 map) =====
  {
    const int b = tid >> 3, jl = (tid >> 1) & 3, gp = tid & 1;
    const int jg = blk & 127, dir = blk >> 7;
    const int j = jg * 4 + jl;
    const int g0 = gp * 2;
    const int len = p.lens[b];
    const float* Whh = dir ? p.W_hh_b : p.W_hh_f;
    const float* xg = dir ? p.xg_b : p.xg_f;
    float* hout = dir ? p.h_b_rev : p.h_f_out;

    // stage this block's 16 W_hh rows (gate g, unit jg*4+rjl) into LDS once
    for (int i = tid; i < 2048; i += 256) {
      int row = i >> 7, f4 = i & 127;
      int g = row >> 2, rjl = row & 3;
      swu[row * 129 + f4] =
          *(const float4*)(Whh + ((size_t)(g * 512 + jg * 4 + rjl)) * 512 + f4 * 4);
    }
    __syncthreads();

    const float4* w04 = &swu[(size_t)(g0 * 4 + jl) * 129];
    const float4* w14 = &swu[(size_t)((g0 + 1) * 4 + jl) * 129];

    float c = 0.f;
    for (int t = 0; t < 64; ++t) {
      size_t xoff = ((size_t)(t * 32 + b)) * 2048 + j;
      float a0 = xg[xoff + (size_t)g0 * 512];
      float a1 = xg[xoff + (size_t)(g0 + 1) * 512];
      if (t > 0) {
        const float* hr = p.h_cur + ((size_t)((((t & 1) ^ 1) * 2 + dir) * 32 + b)) * 512;
#pragma unroll 8
        for (int kc = 0; kc < 128; ++kc) {
          float4 h4 = *(const float4*)(hr + kc * 4);
          float4 w0v = w04[kc];
          float4 w1v = w14[kc];
          a0 = fmaf(h4.x, w0v.x, a0); a0 = fmaf(h4.y, w0v.y, a0);
          a0 = fmaf(h4.z, w0v.z, a0); a0 = fmaf(h4.w, w0v.w, a0);
          a1 = fmaf(h4.x, w1v.x, a1); a1 = fmaf(h4.y, w1v.y, a1);
          a1 = fmaf(h4.z, w1v.z, a1); a1 = fmaf(h4.w, w1v.w, a1);
        }
      }
      gates_lds[b][jl][g0] = a0;
      gates_lds[b][jl][g0 + 1] = a1;
      __syncthreads();
      if (gp == 0) {
        float vi = gates_lds[b][jl][0], vf = gates_lds[b][jl][1];
        float vg = gates_lds[b][jl][2], vo = gates_lds[b][jl][3];
        float hv = 0.f;
        bool m = (t < len);
        if (m) {
          c = sigm(vf) * c + sigm(vi) * tanhf(vg);
          hv = sigm(vo) * tanhf(c);
          p.h_cur[((size_t)(((t & 1) * 2 + dir) * 32 + b)) * 512 + j] = hv;
        }
        hout[((size_t)(t * 32 + b)) * 512 + j] = m ? hv : 0.f;
      }
      grid.sync();
    }
  }

  // stage this block's 12 decoder ctx-weight rows (gate g, unit blk*4+rjl) into LDS.
  // Encoder's final grid.sync (block barrier included) separates last swu reads
  // from these writes; phase A's grid.sync separates writes from first D2 reads.
  for (int i = tid; i < 3072; i += 256) {
    int row = i >> 8, f4 = i & 255;
    int g = row >> 2, rjl = row & 3;
    swu[row * 257 + f4] =
        *(const float4*)(p.Wi + ((size_t)(g * 1024 + blk * 4 + rjl)) * 1536 + 512 + f4 * 4);
  }

  // ===== phase A: enc_out assembly + attE = enc_out@Wa[:1024]+ba =====
  {
    for (int r = 0; r < 8; ++r) {
      int fi = blk * 8192 + r * 1024 + tid * 4;
      int b = fi >> 16, s = (fi >> 10) & 63, d = tid * 4;
      float4 v;
      if (d < 512) {
        v = *(const float4*)(p.h_f_out + ((size_t)(s * 32 + b)) * 512 + d);
      } else {
        int len = p.lens[b];
        int rs = (s < len) ? (len - 1 - s) : s;
        v = *(const float4*)(p.h_b_rev + ((size_t)(rs * 32 + b)) * 512 + (d - 512));
      }
      *(float4*)(p.enc_out + ((size_t)(b * 64 + s)) * 1024 + d) = v;
    }
    if (blk < 64) {
      int idx = blk * 256 + tid;
      int h = idx & 7, s = (idx >> 3) & 63, b = idx >> 9;
      int len = p.lens[b];
      int rs = (s < len) ? (len - 1 - s) : s;
      float acc = p.ba[h];
      const float* hf = p.h_f_out + ((size_t)(s * 32 + b)) * 512;
      const float* hb = p.h_b_rev + ((size_t)(rs * 32 + b)) * 512;
      for (int d = 0; d < 512; ++d) acc = fmaf(hf[d], p.Wa[(size_t)d * 8 + h], acc);
      for (int d = 0; d < 512; ++d) acc = fmaf(hb[d], p.Wa[(size_t)(512 + d) * 8 + h], acc);
      p.attE[(size_t)(b * 64 + s) * 8 + h] = acc;
    }
    grid.sync();
  }

  // ===== decoder: 32 steps, 2 grid.sync each =====
  for (int t = 0; t < T_DEC_; ++t) {
    // --- D1: attention + context (blocks 0..31, one per batch; R1 verbatim) ---
    if (blk < 32) {
      const int b = blk;
      const int len = p.lens[b];
      int h = tid & 7, sl = tid >> 3;
      float qp = 0.f;
      if (t > 0) {
        const float* st = p.state + (size_t)b * 1024 + sl * 32;
        const float* wa = p.Wa + (size_t)(1024 + sl * 32) * 8 + h;
        for (int dd = 0; dd < 32; ++dd) qp = fmaf(st[dd], wa[dd * 8], qp);
      }
      sh_qp[h][sl] = qp;
      __syncthreads();
      if (tid < 8) {
        float sq = 0.f;
        for (int i = 0; i < 32; ++i) sq += sh_qp[tid][i];
        sh_q[tid] = sq;
      }
      __syncthreads();
      if (tid < 64) {
        int s = tid;
        float sc = -1e9f;
        if (s < len) {
          sc = 0.f;
          const float* ae = p.attE + (size_t)(b * 64 + s) * 8;
#pragma unroll
          for (int hh = 0; hh < 8; ++hh) sc = fmaf(p.va[hh], tanhf(ae[hh] + sh_q[hh]), sc);
        }
        float mx = sc;
        for (int off = 32; off; off >>= 1) mx = fmaxf(mx, __shfl_down(mx, off));
        mx = __shfl(mx, 0);
        float e = expf(sc - mx);
        float sm = e;
        for (int off = 32; off; off >>= 1) sm += __shfl_down(sm, off);
        sm = __shfl(sm, 0);
        sh_al[s] = e / sm;
      }
      __syncthreads();
#pragma unroll
      for (int rr = 0; rr < 4; ++rr) {
        int d = tid + rr * 256;
        float cv = 0.f;
        const float* eo = p.enc_out + (size_t)(b * 64) * 1024 + d;
#pragma unroll 8
        for (int s = 0; s < 64; ++s) cv = fmaf(sh_al[s], eo[(size_t)s * 1024], cv);
        p.context[(size_t)b * 1024 + d] = cv;
      }
    }
    grid.sync();
    // --- D2: gi_ctx = ctx @ Wi_ctx^T (LDS weights); thread owns (b, j) like R1 ---
    if (tid < 128) {
      const int b = tid >> 2, jl = tid & 3;
      const int j = blk * 4 + jl;
      const float4* wr4 = &swu[(size_t)(0 + jl) * 257];
      const float4* wz4 = &swu[(size_t)(4 + jl) * 257];
      const float4* wn4 = &swu[(size_t)(8 + jl) * 257];
      const float4* cb = (const float4*)(p.context + (size_t)b * 1024);
      float ar = 0.f, az = 0.f, an = 0.f;
#pragma unroll 8
      for (int kc = 0; kc < 256; ++kc) {
        float4 c4 = cb[kc];
        float4 rv = wr4[kc];
        float4 zv = wz4[kc];
        float4 nv = wn4[kc];
        ar = fmaf(c4.x, rv.x, ar); ar = fmaf(c4.y, rv.y, ar);
        ar = fmaf(c4.z, rv.z, ar); ar = fmaf(c4.w, rv.w, ar);
        az = fmaf(c4.x, zv.x, az); az = fmaf(c4.y, zv.y, az);
        az = fmaf(c4.z, zv.z, az); az = fmaf(c4.w, zv.w, az);
        an = fmaf(c4.x, nv.x, an); an = fmaf(c4.y, nv.y, an);
        an = fmaf(c4.z, nv.z, an); an = fmaf(c4.w, nv.w, an);
      }
      const float* gpre = p.gi_pre + (size_t)(t * 32 + b) * 3072;
      float gr = ar + gpre[j];
      float gz = az + gpre[1024 + j];
      float gn = an + gpre[2048 + j];
      float r = sigm(gr + p.bh[j]);
      float z = sigm(gz + p.bh[1024 + j]);
      float n = tanhf(gn + r * p.bh[2048 + j]);
      float hv = (1.f - z) * n;
      p.state[(size_t)b * 1024 + j] = hv;
      p.a_cls[(size_t)(t * 32 + b) * 1024 + j] = f2bf(hv);
    }
    grid.sync();
  }
}

// ---------------- classifier: bf16 MFMA GEMM + bias + relu ----------------
__global__ __launch_bounds__(256) void cls_kernel(const unsigned short* __restrict__ A_bf,
                                                  const unsigned short* __restrict__ W_bf,
                                                  const float* __restrict__ bc,
                                                  float* __restrict__ out) {
  __shared__ __align__(16) unsigned short s_a[128 * 40];
  __shared__ __align__(16) unsigned short s_b[128 * 40];
  const int tid = threadIdx.x;
  const int n0 = blockIdx.x * 128, m0 = blockIdx.y * 128;
  const int lane = tid & 63, wid = tid >> 6;
  const int wm = (wid & 1) * 64, wn = (wid >> 1) * 64;
  const int lr = lane & 15, quad = lane >> 4;

  f32x4_t acc[4][4];
#pragma unroll
  for (int i = 0; i < 4; ++i)
#pragma unroll
    for (int j = 0; j < 4; ++j) acc[i][j] = (f32x4_t){0.f, 0.f, 0.f, 0.f};

  for (int kc = 0; kc < 1024; kc += 32) {
#pragma unroll
    for (int c = tid; c < 512; c += 256) {
      int r = c >> 2, c4 = c & 3;
      *(uint4*)&s_a[r * 40 + c4 * 8] =
          *(const uint4*)&A_bf[(size_t)(m0 + r) * 1024 + kc + c4 * 8];
      *(uint4*)&s_b[r * 40 + c4 * 8] =
          *(const uint4*)&W_bf[(size_t)(n0 + r) * 1024 + kc + c4 * 8];
    }
    __syncthreads();
    bf16x8_t af[4], bfv[4];
#pragma unroll
    for (int i = 0; i < 4; ++i)
      af[i] = __builtin_bit_cast(bf16x8_t,
               *(const uint4*)&s_a[(wm + i * 16 + lr) * 40 + quad * 8]);
#pragma unroll
    for (int j = 0; j < 4; ++j)
      bfv[j] = __builtin_bit_cast(bf16x8_t,
               *(const uint4*)&s_b[(wn + j * 16 + lr) * 40 + quad * 8]);
#pragma unroll
    for (int i = 0; i < 4; ++i)
#pragma unroll
      for (int j = 0; j < 4; ++j)
        acc[i][j] = __builtin_amdgcn_mfma_f32_16x16x32_bf16(af[i], bfv[j], acc[i][j], 0, 0, 0);
    __syncthreads();
  }

#pragma unroll
  for (int j = 0; j < 4; ++j) {
    int col = n0 + wn + j * 16 + lr;
    float bias = bc[col];
#pragma unroll
    for (int i = 0; i < 4; ++i) {
      int rowb = m0 + wm + i * 16 + quad * 4;
#pragma unroll
      for (int r = 0; r < 4; ++r) {
        int row = rowb + r;
        int tt = row >> 5, bb = row & 31;
        float v = acc[i][j][r] + bias;
        v = v > 0.f ? v : 0.f;
        out[((size_t)(bb * 32 + tt)) * 32000 + col] = v;
      }
    }
  }
}

// ---------------- host launcher ----------------
extern "C" void kernel_launch(void* const* d_in, const int* in_sizes, int n_in,
                              void* d_out, int out_size, void* d_ws, size_t ws_size,
                              hipStream_t stream) {
  const int* enc_in = (const int*)d_in[0];
  const int* enc_len = (const int*)d_in[1];
  const int* dec_in = (const int*)d_in[2];
  const float* emb_f = (const float*)d_in[4];
  const float* emb_e = (const float*)d_in[5];
  const float* W_ih_f = (const float*)d_in[6];
  const float* W_hh_f = (const float*)d_in[7];
  const float* b_ih_f = (const float*)d_in[8];
  const float* b_hh_f = (const float*)d_in[9];
  const float* W_ih_b = (const float*)d_in[10];
  const float* W_hh_b = (const float*)d_in[11];
  const float* b_ih_b = (const float*)d_in[12];
  const float* b_hh_b = (const float*)d_in[13];
  const float* Wa = (const float*)d_in[14];
  const float* ba = (const float*)d_in[15];
  const float* va = (const float*)d_in[16];
  const float* Wi_gru = (const float*)d_in[17];
  const float* bi_gru = (const float*)d_in[19];
  const float* bh_gru = (const float*)d_in[20];
  const float* Wc = (const float*)d_in[21];
  const float* bc = (const float*)d_in[22];
  float* out = (float*)d_out;

  char* ws = (char*)d_ws;
  size_t off = 0;
  auto alloc = [&](size_t bytes) -> char* {
    char* p = ws + off;
    off += (bytes + 255) & ~(size_t)255;
    return p;
  };
  float* xg_f   = (float*)alloc((size_t)64 * 32 * 2048 * 4);
  float* xg_b   = (float*)alloc((size_t)64 * 32 * 2048 * 4);
  float* gi_pre = (float*)alloc((size_t)32 * 32 * 3072 * 4);
  float* h_f_out = (float*)alloc((size_t)64 * 32 * 512 * 4);
  float* h_b_rev = (float*)alloc((size_t)64 * 32 * 512 * 4);
  float* enc_out = (float*)alloc((size_t)32 * 64 * 1024 * 4);
  float* attE    = (float*)alloc((size_t)32 * 64 * 8 * 4);
  float* h_cur   = (float*)alloc((size_t)2 * 2 * 32 * 512 * 4);
  float* state   = (float*)alloc((size_t)32 * 1024 * 4);
  float* context = (float*)alloc((size_t)32 * 1024 * 4);
  unsigned short* a_cls = (unsigned short*)alloc((size_t)1024 * 1024 * 2);
  unsigned short* wc_bf = (unsigned short*)alloc((size_t)32000 * 1024 * 2);

  conv_bf16<<<16000, 256, 0, stream>>>(Wc, wc_bf, 4096000);

  gemm_gather<<<dim3(32, 32), 256, 0, stream>>>(emb_f, enc_in, enc_len, W_ih_f, 512,
                                                b_ih_f, b_hh_f, xg_f, 2048, 0);
  gemm_gather<<<dim3(32, 32), 256, 0, stream>>>(emb_f, enc_in, enc_len, W_ih_b, 512,
                                                b_ih_b, b_hh_b, xg_b, 2048, 1);
  gemm_gather<<<dim3(48, 16), 256, 0, stream>>>(emb_e, dec_in, enc_len, Wi_gru, 1536,
                                                bi_gru, nullptr, gi_pre, 3072, 2);

  CoopParams cp;
  cp.lens = enc_len; cp.Wa = Wa; cp.ba = ba; cp.va = va;
  cp.Wi = Wi_gru; cp.bh = bh_gru;
  cp.W_hh_f = W_hh_f; cp.W_hh_b = W_hh_b;
  cp.xg_f = xg_f; cp.xg_b = xg_b; cp.gi_pre = gi_pre;
  cp.h_f_out = h_f_out; cp.h_b_rev = h_b_rev; cp.enc_out = enc_out; cp.attE = attE;
  cp.h_cur = h_cur; cp.state = state; cp.context = context; cp.a_cls = a_cls;
  void* args[] = { &cp };
  hipLaunchCooperativeKernel((const void*)coop_kernel, dim3(256), dim3(256), args, 0, stream);

  cls_kernel<<<dim3(250, 8), 256, 0, stream>>>(a_cls, wc_bf, bc, out);
}

// Round 2
// 3617.133 us; speedup vs baseline: 1.7185x; 1.7185x over previous
//
#include <hip/hip_runtime.h>
#include <cstddef>

#define B_ 32
#define T_ENC_ 64
#define T_DEC_ 32
#define ENC_H_ 512
#define DEC_H_ 1024
#define V_E_ 32000

typedef __bf16 bf16x8_t __attribute__((ext_vector_type(8)));
typedef float f32x4_t __attribute__((ext_vector_type(4)));

__device__ __forceinline__ float sigm(float x) { return 1.f / (1.f + expf(-x)); }

__device__ __forceinline__ unsigned short f2bf(float f) {
  union { float f; unsigned u; } v; v.f = f;
  unsigned u = v.u;
  unsigned r = (u + 0x7fffu + ((u >> 16) & 1u)) >> 16;
  return (unsigned short)r;
}

// ---- agent-scope (cross-XCD coherent, L2-bypassing) access helpers ----
__device__ __forceinline__ void st_f32_ag(float* p, float v) {
  __hip_atomic_store(p, v, __ATOMIC_RELAXED, __HIP_MEMORY_SCOPE_AGENT);
}
__device__ __forceinline__ void st_f32x2_ag(float* p, float a, float b) {
  float2 t; t.x = a; t.y = b;
  __hip_atomic_store((unsigned long long*)p, __builtin_bit_cast(unsigned long long, t),
                     __ATOMIC_RELAXED, __HIP_MEMORY_SCOPE_AGENT);
}
__device__ __forceinline__ float2 ld_f32x2_ag(const float* p) {
  unsigned long long u = __hip_atomic_load((const unsigned long long*)p,
                                           __ATOMIC_RELAXED, __HIP_MEMORY_SCOPE_AGENT);
  return __builtin_bit_cast(float2, u);
}

// ---- lightweight grid barrier: monotonic-epoch counter, no cache maintenance.
// Correctness: __syncthreads() drains vmcnt(0) for ALL waves of the block before
// thread 0's arrival add (compiler emits s_waitcnt vmcnt(0) before s_barrier), so
// every agent-scope data store of this block is globally visible before arrival.
__device__ __forceinline__ void gbar(unsigned* cnt, unsigned ep) {
  __syncthreads();
  if (threadIdx.x == 0) {
    __hip_atomic_fetch_add(cnt, 1u, __ATOMIC_RELAXED, __HIP_MEMORY_SCOPE_AGENT);
    const unsigned tgt = ep * 256u;
    while (__hip_atomic_load(cnt, __ATOMIC_RELAXED, __HIP_MEMORY_SCOPE_AGENT) < tgt)
      __builtin_amdgcn_s_sleep(1);
  }
  __syncthreads();
}

// ---------------- Wc fp32 -> bf16 convert ----------------
__global__ __launch_bounds__(256) void conv_bf16(const float* __restrict__ src,
                                                 unsigned short* __restrict__ dst, int n8) {
  int i = blockIdx.x * 256 + threadIdx.x;
  if (i >= n8) return;
  float4 v0 = *(const float4*)(src + (size_t)i * 8);
  float4 v1 = *(const float4*)(src + (size_t)i * 8 + 4);
  union { unsigned short u[8]; uint4 v; } o;
  o.u[0] = f2bf(v0.x); o.u[1] = f2bf(v0.y); o.u[2] = f2bf(v0.z); o.u[3] = f2bf(v0.w);
  o.u[4] = f2bf(v1.x); o.u[5] = f2bf(v1.y); o.u[6] = f2bf(v1.z); o.u[7] = f2bf(v1.w);
  *(uint4*)(dst + (size_t)i * 8) = o.v;
}

// ---------------- fp32 tiled GEMM with embedding-gather A ----------------
__global__ __launch_bounds__(256) void gemm_gather(
    const float* __restrict__ emb, const int* __restrict__ idx,
    const int* __restrict__ lens, const float* __restrict__ W, int ldw,
    const float* __restrict__ bias1, const float* __restrict__ bias2,
    float* __restrict__ out, int N, int mode) {
  __shared__ __align__(16) float s_at[16][68];
  __shared__ __align__(16) float s_bt[16][68];
  __shared__ int gidx[64];
  const int tid = threadIdx.x;
  const int tx = tid & 15, ty = tid >> 4;
  const int n0 = blockIdx.x * 64, m0 = blockIdx.y * 64;

  if (tid < 64) {
    int m = m0 + tid;
    int t = m >> 5, b = m & 31;
    int gi;
    if (mode == 0) gi = idx[b * 64 + t];
    else if (mode == 1) {
      int len = lens[b];
      int tt = (t < len) ? (len - 1 - t) : t;
      gi = idx[b * 64 + tt];
    } else gi = idx[b * 32 + t];
    gidx[tid] = gi;
  }
  __syncthreads();

  float acc[4][4] = {};
  const int r = tid >> 2, c4 = tid & 3;
  for (int kc = 0; kc < 512; kc += 16) {
    float4 av = *(const float4*)(emb + (size_t)gidx[r] * 512 + kc + c4 * 4);
    float4 bv = *(const float4*)(W + (size_t)(n0 + r) * ldw + kc + c4 * 4);
    s_at[c4 * 4 + 0][r] = av.x; s_at[c4 * 4 + 1][r] = av.y;
    s_at[c4 * 4 + 2][r] = av.z; s_at[c4 * 4 + 3][r] = av.w;
    s_bt[c4 * 4 + 0][r] = bv.x; s_bt[c4 * 4 + 1][r] = bv.y;
    s_bt[c4 * 4 + 2][r] = bv.z; s_bt[c4 * 4 + 3][r] = bv.w;
    __syncthreads();
#pragma unroll
    for (int kk = 0; kk < 16; ++kk) {
      float4 a4 = *(const float4*)&s_at[kk][ty * 4];
      float4 b4 = *(const float4*)&s_bt[kk][tx * 4];
      float avv[4] = {a4.x, a4.y, a4.z, a4.w};
      float bvv[4] = {b4.x, b4.y, b4.z, b4.w};
#pragma unroll
      for (int i = 0; i < 4; ++i)
#pragma unroll
        for (int j = 0; j < 4; ++j)
          acc[i][j] = fmaf(avv[i], bvv[j], acc[i][j]);
    }
    __syncthreads();
  }
#pragma unroll
  for (int i = 0; i < 4; ++i) {
    int m = m0 + ty * 4 + i;
#pragma unroll
    for (int j = 0; j < 4; ++j) {
      int n = n0 + tx * 4 + j;
      float v = acc[i][j] + bias1[n] + (bias2 ? bias2[n] : 0.f);
      out[(size_t)m * N + n] = v;
    }
  }
}

// ---------------- cooperative kernel: recurrences ----------------
struct CoopParams {
  const int* lens;
  const float* Wa; const float* ba; const float* va;
  const float* Wi; const float* bh;
  const float* W_hh_f; const float* W_hh_b;
  const float* xg_f; const float* xg_b; const float* gi_pre;
  float* h_f_out; float* h_b_rev; float* enc_out; float* attE;
  float* state; float* context;
  unsigned short* a_cls;
  unsigned* bar;
};

__global__ __launch_bounds__(256) void coop_kernel(CoopParams p) {
  const int tid = threadIdx.x;
  const int blk = blockIdx.x;
  unsigned ep = 0;

  // weight stage: union of encoder [16][129] f4 (2064) and decoder [12][257] f4 (3084)
  __shared__ __align__(16) float4 swu[3084];
  __shared__ float gates_lds[32][4][4];
  __shared__ float sh_qp[8][33];
  __shared__ float sh_q[8];
  __shared__ float sh_al[64];

  // ===== encoder bi-LSTM: weights LDS-resident, 1 barrier/step =====
  {
    const int b = tid >> 3, jl = (tid >> 1) & 3, gp = tid & 1;
    const int jg = blk & 127, dir = blk >> 7;
    const int j = jg * 4 + jl;
    const int g0 = gp * 2;
    const int len = p.lens[b];
    const float* Whh = dir ? p.W_hh_b : p.W_hh_f;
    const float* xg = dir ? p.xg_b : p.xg_f;
    float* hout = dir ? p.h_b_rev : p.h_f_out;

    // stage this block's 16 W_hh rows (gate g, unit jg*4+rjl) into LDS once
    for (int i = tid; i < 2048; i += 256) {
      int row = i >> 7, f4 = i & 127;
      int g = row >> 2, rjl = row & 3;
      swu[row * 129 + f4] =
          *(const float4*)(Whh + ((size_t)(g * 512 + jg * 4 + rjl)) * 512 + f4 * 4);
    }
    __syncthreads();

    const float4* w04 = &swu[(size_t)(g0 * 4 + jl) * 129];
    const float4* w14 = &swu[(size_t)((g0 + 1) * 4 + jl) * 129];

    float c = 0.f;
    for (int t = 0; t < 64; ++t) {
      size_t xoff = ((size_t)(t * 32 + b)) * 2048 + j;
      float a0 = xg[xoff + (size_t)g0 * 512];
      float a1 = xg[xoff + (size_t)(g0 + 1) * 512];
      if (t > 0) {
        // h(t-1) slot written exactly once (agent stores) and never read before
        // by this XCD -> normal cached float4 loads are coherent.
        // For t-1 >= len the slot is zero and the resulting gates are discarded
        // by the mask below, matching the old h_cur retention semantics.
        const float* hr = hout + ((size_t)((t - 1) * 32 + b)) * 512;
#pragma unroll 8
        for (int kc = 0; kc < 128; ++kc) {
          float4 h4 = *(const float4*)(hr + kc * 4);
          float4 w0v = w04[kc];
          float4 w1v = w14[kc];
          a0 = fmaf(h4.x, w0v.x, a0); a0 = fmaf(h4.y, w0v.y, a0);
          a0 = fmaf(h4.z, w0v.z, a0); a0 = fmaf(h4.w, w0v.w, a0);
          a1 = fmaf(h4.x, w1v.x, a1); a1 = fmaf(h4.y, w1v.y, a1);
          a1 = fmaf(h4.z, w1v.z, a1); a1 = fmaf(h4.w, w1v.w, a1);
        }
      }
      gates_lds[b][jl][g0] = a0;
      gates_lds[b][jl][g0 + 1] = a1;
      __syncthreads();
      if (gp == 0) {
        float vi = gates_lds[b][jl][0], vf = gates_lds[b][jl][1];
        float vg = gates_lds[b][jl][2], vo = gates_lds[b][jl][3];
        float hv = 0.f;
        bool m = (t < len);
        if (m) {
          c = sigm(vf) * c + sigm(vi) * tanhf(vg);
          hv = sigm(vo) * tanhf(c);
        }
        st_f32_ag(&hout[((size_t)(t * 32 + b)) * 512 + j], m ? hv : 0.f);
      }
      ++ep; gbar(p.bar, ep);
    }
  }

  // stage this block's 12 decoder ctx-weight rows (gate g, unit blk*4+rjl) into LDS.
  // Encoder's final gbar (__syncthreads) separates last swu reads from these writes;
  // phase A's gbar separates writes from first D2 reads.
  for (int i = tid; i < 3072; i += 256) {
    int row = i >> 8, f4 = i & 255;
    int g = row >> 2, rjl = row & 3;
    swu[row * 257 + f4] =
        *(const float4*)(p.Wi + ((size_t)(g * 1024 + blk * 4 + rjl)) * 1536 + 512 + f4 * 4);
  }

  // ===== phase A: enc_out assembly + attE = enc_out@Wa[:1024]+ba =====
  {
    for (int r = 0; r < 8; ++r) {
      int fi = blk * 8192 + r * 1024 + tid * 4;
      int b = fi >> 16, s = (fi >> 10) & 63, d = tid * 4;
      float4 v;
      if (d < 512) {
        v = *(const float4*)(p.h_f_out + ((size_t)(s * 32 + b)) * 512 + d);
      } else {
        int len = p.lens[b];
        int rs = (s < len) ? (len - 1 - s) : s;
        v = *(const float4*)(p.h_b_rev + ((size_t)(rs * 32 + b)) * 512 + (d - 512));
      }
      float* ob = p.enc_out + ((size_t)(b * 64 + s)) * 1024 + d;
      st_f32x2_ag(ob, v.x, v.y);        // write-through so decoder XCDs see it;
      st_f32x2_ag(ob + 2, v.z, v.w);    // decoder reads stay L2-cacheable (read-only)
    }
    if (blk < 64) {
      int idx = blk * 256 + tid;
      int h = idx & 7, s = (idx >> 3) & 63, b = idx >> 9;
      int len = p.lens[b];
      int rs = (s < len) ? (len - 1 - s) : s;
      float acc = p.ba[h];
      const float* hf = p.h_f_out + ((size_t)(s * 32 + b)) * 512;
      const float* hb = p.h_b_rev + ((size_t)(rs * 32 + b)) * 512;
      for (int d = 0; d < 512; ++d) acc = fmaf(hf[d], p.Wa[(size_t)d * 8 + h], acc);
      for (int d = 0; d < 512; ++d) acc = fmaf(hb[d], p.Wa[(size_t)(512 + d) * 8 + h], acc);
      st_f32_ag(&p.attE[(size_t)(b * 64 + s) * 8 + h], acc);
    }
    ++ep; gbar(p.bar, ep);
  }

  // ===== decoder: 32 steps, 2 barriers each =====
  for (int t = 0; t < T_DEC_; ++t) {
    // --- D1: attention + context (blocks 0..31, one per batch) ---
    if (blk < 32) {
      const int b = blk;
      const int len = p.lens[b];
      int h = tid & 7, sl = tid >> 3;
      float qp = 0.f;
      if (t > 0) {
        const float* st = p.state + (size_t)b * 1024 + sl * 32;
        const float* wa = p.Wa + (size_t)(1024 + sl * 32) * 8 + h;
#pragma unroll
        for (int dd = 0; dd < 16; ++dd) {
          float2 sv = ld_f32x2_ag(st + dd * 2);   // state rewritten each step -> sc1 loads
          qp = fmaf(sv.x, wa[(dd * 2) * 8], qp);
          qp = fmaf(sv.y, wa[(dd * 2 + 1) * 8], qp);
        }
      }
      sh_qp[h][sl] = qp;
      __syncthreads();
      if (tid < 8) {
        float sq = 0.f;
        for (int i = 0; i < 32; ++i) sq += sh_qp[tid][i];
        sh_q[tid] = sq;
      }
      __syncthreads();
      if (tid < 64) {
        int s = tid;
        float sc = -1e9f;
        if (s < len) {
          sc = 0.f;
          const float* ae = p.attE + (size_t)(b * 64 + s) * 8;   // read-only after phase A
#pragma unroll
          for (int hh = 0; hh < 8; ++hh) sc = fmaf(p.va[hh], tanhf(ae[hh] + sh_q[hh]), sc);
        }
        float mx = sc;
        for (int off = 32; off; off >>= 1) mx = fmaxf(mx, __shfl_down(mx, off));
        mx = __shfl(mx, 0);
        float e = expf(sc - mx);
        float sm = e;
        for (int off = 32; off; off >>= 1) sm += __shfl_down(sm, off);
        sm = __shfl(sm, 0);
        sh_al[s] = e / sm;
      }
      __syncthreads();
#pragma unroll
      for (int rr = 0; rr < 4; ++rr) {
        int d = tid + rr * 256;
        float cv = 0.f;
        const float* eo = p.enc_out + (size_t)(b * 64) * 1024 + d;  // read-only, L2-cached
#pragma unroll 8
        for (int s = 0; s < 64; ++s) cv = fmaf(sh_al[s], eo[(size_t)s * 1024], cv);
        st_f32_ag(&p.context[(size_t)b * 1024 + d], cv);
      }
    }
    ++ep; gbar(p.bar, ep);
    // --- D2: gi_ctx = ctx @ Wi_ctx^T (LDS weights); thread owns (b, j) ---
    if (tid < 128) {
      const int b = tid >> 2, jl = tid & 3;
      const int j = blk * 4 + jl;
      const float4* wr4 = &swu[(size_t)(0 + jl) * 257];
      const float4* wz4 = &swu[(size_t)(4 + jl) * 257];
      const float4* wn4 = &swu[(size_t)(8 + jl) * 257];
      const float* cbase = p.context + (size_t)b * 1024;
      float ar = 0.f, az = 0.f, an = 0.f;
#pragma unroll 8
      for (int kc = 0; kc < 256; ++kc) {
        float2 cA = ld_f32x2_ag(cbase + kc * 4);       // context rewritten each step
        float2 cB = ld_f32x2_ag(cbase + kc * 4 + 2);
        float4 rv = wr4[kc];
        float4 zv = wz4[kc];
        float4 nv = wn4[kc];
        ar = fmaf(cA.x, rv.x, ar); ar = fmaf(cA.y, rv.y, ar);
        ar = fmaf(cB.x, rv.z, ar); ar = fmaf(cB.y, rv.w, ar);
        az = fmaf(cA.x, zv.x, az); az = fmaf(cA.y, zv.y, az);
        az = fmaf(cB.x, zv.z, az); az = fmaf(cB.y, zv.w, az);
        an = fmaf(cA.x, nv.x, an); an = fmaf(cA.y, nv.y, an);
        an = fmaf(cB.x, nv.z, an); an = fmaf(cB.y, nv.w, an);
      }
      const float* gpre = p.gi_pre + (size_t)(t * 32 + b) * 3072;
      float gr = ar + gpre[j];
      float gz = az + gpre[1024 + j];
      float gn = an + gpre[2048 + j];
      float r = sigm(gr + p.bh[j]);
      float z = sigm(gz + p.bh[1024 + j]);
      float n = tanhf(gn + r * p.bh[2048 + j]);
      float hv = (1.f - z) * n;
      st_f32_ag(&p.state[(size_t)b * 1024 + j], hv);
      p.a_cls[(size_t)(t * 32 + b) * 1024 + j] = f2bf(hv);  // cross-kernel: normal store
    }
    ++ep; gbar(p.bar, ep);
  }
}

// ---------------- classifier: bf16 MFMA GEMM + bias + relu ----------------
__global__ __launch_bounds__(256) void cls_kernel(const unsigned short* __restrict__ A_bf,
                                                  const unsigned short* __restrict__ W_bf,
                                                  const float* __restrict__ bc,
                                                  float* __restrict__ out) {
  __shared__ __align__(16) unsigned short s_a[128 * 40];
  __shared__ __align__(16) unsigned short s_b[128 * 40];
  const int tid = threadIdx.x;
  const int n0 = blockIdx.x * 128, m0 = blockIdx.y * 128;
  const int lane = tid & 63, wid = tid >> 6;
  const int wm = (wid & 1) * 64, wn = (wid >> 1) * 64;
  const int lr = lane & 15, quad = lane >> 4;

  f32x4_t acc[4][4];
#pragma unroll
  for (int i = 0; i < 4; ++i)
#pragma unroll
    for (int j = 0; j < 4; ++j) acc[i][j] = (f32x4_t){0.f, 0.f, 0.f, 0.f};

  for (int kc = 0; kc < 1024; kc += 32) {
#pragma unroll
    for (int c = tid; c < 512; c += 256) {
      int r = c >> 2, c4 = c & 3;
      *(uint4*)&s_a[r * 40 + c4 * 8] =
          *(const uint4*)&A_bf[(size_t)(m0 + r) * 1024 + kc + c4 * 8];
      *(uint4*)&s_b[r * 40 + c4 * 8] =
          *(const uint4*)&W_bf[(size_t)(n0 + r) * 1024 + kc + c4 * 8];
    }
    __syncthreads();
    bf16x8_t af[4], bfv[4];
#pragma unroll
    for (int i = 0; i < 4; ++i)
      af[i] = __builtin_bit_cast(bf16x8_t,
               *(const uint4*)&s_a[(wm + i * 16 + lr) * 40 + quad * 8]);
#pragma unroll
    for (int j = 0; j < 4; ++j)
      bfv[j] = __builtin_bit_cast(bf16x8_t,
               *(const uint4*)&s_b[(wn + j * 16 + lr) * 40 + quad * 8]);
#pragma unroll
    for (int i = 0; i < 4; ++i)
#pragma unroll
      for (int j = 0; j < 4; ++j)
        acc[i][j] = __builtin_amdgcn_mfma_f32_16x16x32_bf16(af[i], bfv[j], acc[i][j], 0, 0, 0);
    __syncthreads();
  }

#pragma unroll
  for (int j = 0; j < 4; ++j) {
    int col = n0 + wn + j * 16 + lr;
    float bias = bc[col];
#pragma unroll
    for (int i = 0; i < 4; ++i) {
      int rowb = m0 + wm + i * 16 + quad * 4;
#pragma unroll
      for (int r = 0; r < 4; ++r) {
        int row = rowb + r;
        int tt = row >> 5, bb = row & 31;
        float v = acc[i][j][r] + bias;
        v = v > 0.f ? v : 0.f;
        out[((size_t)(bb * 32 + tt)) * 32000 + col] = v;
      }
    }
  }
}

// ---------------- host launcher ----------------
extern "C" void kernel_launch(void* const* d_in, const int* in_sizes, int n_in,
                              void* d_out, int out_size, void* d_ws, size_t ws_size,
                              hipStream_t stream) {
  const int* enc_in = (const int*)d_in[0];
  const int* enc_len = (const int*)d_in[1];
  const int* dec_in = (const int*)d_in[2];
  const float* emb_f = (const float*)d_in[4];
  const float* emb_e = (const float*)d_in[5];
  const float* W_ih_f = (const float*)d_in[6];
  const float* W_hh_f = (const float*)d_in[7];
  const float* b_ih_f = (const float*)d_in[8];
  const float* b_hh_f = (const float*)d_in[9];
  const float* W_ih_b = (const float*)d_in[10];
  const float* W_hh_b = (const float*)d_in[11];
  const float* b_ih_b = (const float*)d_in[12];
  const float* b_hh_b = (const float*)d_in[13];
  const float* Wa = (const float*)d_in[14];
  const float* ba = (const float*)d_in[15];
  const float* va = (const float*)d_in[16];
  const float* Wi_gru = (const float*)d_in[17];
  const float* bi_gru = (const float*)d_in[19];
  const float* bh_gru = (const float*)d_in[20];
  const float* Wc = (const float*)d_in[21];
  const float* bc = (const float*)d_in[22];
  float* out = (float*)d_out;

  char* ws = (char*)d_ws;
  size_t off = 0;
  auto alloc = [&](size_t bytes) -> char* {
    char* p = ws + off;
    off += (bytes + 255) & ~(size_t)255;
    return p;
  };
  float* xg_f   = (float*)alloc((size_t)64 * 32 * 2048 * 4);
  float* xg_b   = (float*)alloc((size_t)64 * 32 * 2048 * 4);
  float* gi_pre = (float*)alloc((size_t)32 * 32 * 3072 * 4);
  float* h_f_out = (float*)alloc((size_t)64 * 32 * 512 * 4);
  float* h_b_rev = (float*)alloc((size_t)64 * 32 * 512 * 4);
  float* enc_out = (float*)alloc((size_t)32 * 64 * 1024 * 4);
  float* attE    = (float*)alloc((size_t)32 * 64 * 8 * 4);
  float* state   = (float*)alloc((size_t)32 * 1024 * 4);
  float* context = (float*)alloc((size_t)32 * 1024 * 4);
  unsigned short* a_cls = (unsigned short*)alloc((size_t)1024 * 1024 * 2);
  unsigned short* wc_bf = (unsigned short*)alloc((size_t)32000 * 1024 * 2);
  unsigned* bar = (unsigned*)alloc(256);

  hipMemsetAsync(bar, 0, 256, stream);

  conv_bf16<<<16000, 256, 0, stream>>>(Wc, wc_bf, 4096000);

  gemm_gather<<<dim3(32, 32), 256, 0, stream>>>(emb_f, enc_in, enc_len, W_ih_f, 512,
                                                b_ih_f, b_hh_f, xg_f, 2048, 0);
  gemm_gather<<<dim3(32, 32), 256, 0, stream>>>(emb_f, enc_in, enc_len, W_ih_b, 512,
                                                b_ih_b, b_hh_b, xg_b, 2048, 1);
  gemm_gather<<<dim3(48, 16), 256, 0, stream>>>(emb_e, dec_in, enc_len, Wi_gru, 1536,
                                                bi_gru, nullptr, gi_pre, 3072, 2);

  CoopParams cp;
  cp.lens = enc_len; cp.Wa = Wa; cp.ba = ba; cp.va = va;
  cp.Wi = Wi_gru; cp.bh = bh_gru;
  cp.W_hh_f = W_hh_f; cp.W_hh_b = W_hh_b;
  cp.xg_f = xg_f; cp.xg_b = xg_b; cp.gi_pre = gi_pre;
  cp.h_f_out = h_f_out; cp.h_b_rev = h_b_rev; cp.enc_out = enc_out; cp.attE = attE;
  cp.state = state; cp.context = context; cp.a_cls = a_cls;
  cp.bar = bar;
  void* args[] = { &cp };
  hipLaunchCooperativeKernel((const void*)coop_kernel, dim3(256), dim3(256), args, 0, stream);

  cls_kernel<<<dim3(250, 8), 256, 0, stream>>>(a_cls, wc_bf, bc, out);
}

// Round 3
// 2489.738 us; speedup vs baseline: 2.4967x; 1.4528x over previous
//
#include <hip/hip_runtime.h>
#include <cstddef>

#define B_ 32
#define T_ENC_ 64
#define T_DEC_ 32
#define ENC_H_ 512
#define DEC_H_ 1024
#define V_E_ 32000

typedef __bf16 bf16x8_t __attribute__((ext_vector_type(8)));
typedef float f32x4_t __attribute__((ext_vector_type(4)));

__device__ __forceinline__ float sigm(float x) { return 1.f / (1.f + expf(-x)); }

__device__ __forceinline__ unsigned short f2bf(float f) {
  union { float f; unsigned u; } v; v.f = f;
  unsigned u = v.u;
  unsigned r = (u + 0x7fffu + ((u >> 16) & 1u)) >> 16;
  return (unsigned short)r;
}

// ---- agent-scope (cross-XCD coherent, L2-bypassing) store helpers ----
__device__ __forceinline__ void st_f32_ag(float* p, float v) {
  __hip_atomic_store(p, v, __ATOMIC_RELAXED, __HIP_MEMORY_SCOPE_AGENT);
}
__device__ __forceinline__ void st_f32x2_ag(float* p, float a, float b) {
  float2 t; t.x = a; t.y = b;
  __hip_atomic_store((unsigned long long*)p, __builtin_bit_cast(unsigned long long, t),
                     __ATOMIC_RELAXED, __HIP_MEMORY_SCOPE_AGENT);
}

// ---- contention-free grid barrier: per-block arrival slots + master aggregate.
// No atomic RMW anywhere: 255 parallel slot stores, block 0's threads poll one
// slot each, thread 0 publishes release word (slots[0]). Monotonic epochs.
// Correctness: __syncthreads() drains vmcnt(0) for ALL waves of the block before
// the leader's slot store, so every agent-scope data store of this block is
// globally visible before arrival is signaled.
__device__ __forceinline__ void gbar(unsigned* slots, unsigned ep) {
  __syncthreads();
  if (blockIdx.x == 0) {
    if (threadIdx.x > 0) {
      while (__hip_atomic_load(&slots[threadIdx.x], __ATOMIC_RELAXED,
                               __HIP_MEMORY_SCOPE_AGENT) < ep)
        __builtin_amdgcn_s_sleep(1);
    }
    __syncthreads();
    if (threadIdx.x == 0)
      __hip_atomic_store(&slots[0], ep, __ATOMIC_RELAXED, __HIP_MEMORY_SCOPE_AGENT);
  } else {
    if (threadIdx.x == 0) {
      __hip_atomic_store(&slots[blockIdx.x], ep, __ATOMIC_RELAXED,
                         __HIP_MEMORY_SCOPE_AGENT);
      while (__hip_atomic_load(&slots[0], __ATOMIC_RELAXED,
                               __HIP_MEMORY_SCOPE_AGENT) < ep)
        __builtin_amdgcn_s_sleep(1);
    }
    __syncthreads();
  }
}

// ---------------- Wc fp32 -> bf16 convert ----------------
__global__ __launch_bounds__(256) void conv_bf16(const float* __restrict__ src,
                                                 unsigned short* __restrict__ dst, int n8) {
  int i = blockIdx.x * 256 + threadIdx.x;
  if (i >= n8) return;
  float4 v0 = *(const float4*)(src + (size_t)i * 8);
  float4 v1 = *(const float4*)(src + (size_t)i * 8 + 4);
  union { unsigned short u[8]; uint4 v; } o;
  o.u[0] = f2bf(v0.x); o.u[1] = f2bf(v0.y); o.u[2] = f2bf(v0.z); o.u[3] = f2bf(v0.w);
  o.u[4] = f2bf(v1.x); o.u[5] = f2bf(v1.y); o.u[6] = f2bf(v1.z); o.u[7] = f2bf(v1.w);
  *(uint4*)(dst + (size_t)i * 8) = o.v;
}

// ---------------- fp32 tiled GEMM with embedding-gather A ----------------
__global__ __launch_bounds__(256) void gemm_gather(
    const float* __restrict__ emb, const int* __restrict__ idx,
    const int* __restrict__ lens, const float* __restrict__ W, int ldw,
    const float* __restrict__ bias1, const float* __restrict__ bias2,
    float* __restrict__ out, int N, int mode) {
  __shared__ __align__(16) float s_at[16][68];
  __shared__ __align__(16) float s_bt[16][68];
  __shared__ int gidx[64];
  const int tid = threadIdx.x;
  const int tx = tid & 15, ty = tid >> 4;
  const int n0 = blockIdx.x * 64, m0 = blockIdx.y * 64;

  if (tid < 64) {
    int m = m0 + tid;
    int t = m >> 5, b = m & 31;
    int gi;
    if (mode == 0) gi = idx[b * 64 + t];
    else if (mode == 1) {
      int len = lens[b];
      int tt = (t < len) ? (len - 1 - t) : t;
      gi = idx[b * 64 + tt];
    } else gi = idx[b * 32 + t];
    gidx[tid] = gi;
  }
  __syncthreads();

  float acc[4][4] = {};
  const int r = tid >> 2, c4 = tid & 3;
  for (int kc = 0; kc < 512; kc += 16) {
    float4 av = *(const float4*)(emb + (size_t)gidx[r] * 512 + kc + c4 * 4);
    float4 bv = *(const float4*)(W + (size_t)(n0 + r) * ldw + kc + c4 * 4);
    s_at[c4 * 4 + 0][r] = av.x; s_at[c4 * 4 + 1][r] = av.y;
    s_at[c4 * 4 + 2][r] = av.z; s_at[c4 * 4 + 3][r] = av.w;
    s_bt[c4 * 4 + 0][r] = bv.x; s_bt[c4 * 4 + 1][r] = bv.y;
    s_bt[c4 * 4 + 2][r] = bv.z; s_bt[c4 * 4 + 3][r] = bv.w;
    __syncthreads();
#pragma unroll
    for (int kk = 0; kk < 16; ++kk) {
      float4 a4 = *(const float4*)&s_at[kk][ty * 4];
      float4 b4 = *(const float4*)&s_bt[kk][tx * 4];
      float avv[4] = {a4.x, a4.y, a4.z, a4.w};
      float bvv[4] = {b4.x, b4.y, b4.z, b4.w};
#pragma unroll
      for (int i = 0; i < 4; ++i)
#pragma unroll
        for (int j = 0; j < 4; ++j)
          acc[i][j] = fmaf(avv[i], bvv[j], acc[i][j]);
    }
    __syncthreads();
  }
#pragma unroll
  for (int i = 0; i < 4; ++i) {
    int m = m0 + ty * 4 + i;
#pragma unroll
    for (int j = 0; j < 4; ++j) {
      int n = n0 + tx * 4 + j;
      float v = acc[i][j] + bias1[n] + (bias2 ? bias2[n] : 0.f);
      out[(size_t)m * N + n] = v;
    }
  }
}

// ---------------- cooperative kernel: recurrences ----------------
struct CoopParams {
  const int* lens;
  const float* Wa; const float* ba; const float* va;
  const float* Wi; const float* bh;
  const float* W_hh_f; const float* W_hh_b;
  const float* xg_f; const float* xg_b; const float* gi_pre;
  float* h_f_out; float* h_b_rev; float* enc_out; float* attE;
  float* ctxbuf;  // [T_DEC][32][1024] rotating: slot t written step t (agent), read step t (normal)
  float* stbuf;   // [T_DEC][32][1024] rotating: slot t written D2(t), read D1(t+1)
  unsigned short* a_cls;
  unsigned* slots;
};

__global__ __launch_bounds__(256) void coop_kernel(CoopParams p) {
  const int tid = threadIdx.x;
  const int blk = blockIdx.x;
  unsigned ep = 0;

  // weight stage: union of encoder [16][129] f4 (2064) and decoder [12][257] f4 (3084)
  __shared__ __align__(16) float4 swu[3084];
  __shared__ float gates_lds[32][4][4];
  __shared__ float sh_qp[8][33];
  __shared__ float sh_q[8];
  __shared__ float sh_al[64];
  __shared__ float red[32][4][2][3];

  // ===== encoder bi-LSTM: weights LDS-resident, 1 barrier/step =====
  {
    const int b = tid >> 3, jl = (tid >> 1) & 3, gp = tid & 1;
    const int jg = blk & 127, dir = blk >> 7;
    const int j = jg * 4 + jl;
    const int g0 = gp * 2;
    const int len = p.lens[b];
    const float* Whh = dir ? p.W_hh_b : p.W_hh_f;
    const float* xg = dir ? p.xg_b : p.xg_f;
    float* hout = dir ? p.h_b_rev : p.h_f_out;

    // stage this block's 16 W_hh rows (gate g, unit jg*4+rjl) into LDS once
    for (int i = tid; i < 2048; i += 256) {
      int row = i >> 7, f4 = i & 127;
      int g = row >> 2, rjl = row & 3;
      swu[row * 129 + f4] =
          *(const float4*)(Whh + ((size_t)(g * 512 + jg * 4 + rjl)) * 512 + f4 * 4);
    }
    __syncthreads();

    const float4* w04 = &swu[(size_t)(g0 * 4 + jl) * 129];
    const float4* w14 = &swu[(size_t)((g0 + 1) * 4 + jl) * 129];

    float c = 0.f;
    for (int t = 0; t < 64; ++t) {
      size_t xoff = ((size_t)(t * 32 + b)) * 2048 + j;
      float a0 = xg[xoff + (size_t)g0 * 512];
      float a1 = xg[xoff + (size_t)(g0 + 1) * 512];
      if (t > 0) {
        // h(t-1) slot written exactly once (agent stores) at step t-1, first read
        // here -> never-before-cached address -> normal cached loads are coherent.
        // For t-1 >= len the slot is zero; resulting gates discarded by mask below.
        const float* hr = hout + ((size_t)((t - 1) * 32 + b)) * 512;
#pragma unroll 16
        for (int kc = 0; kc < 128; ++kc) {
          float4 h4 = *(const float4*)(hr + kc * 4);
          float4 w0v = w04[kc];
          float4 w1v = w14[kc];
          a0 = fmaf(h4.x, w0v.x, a0); a0 = fmaf(h4.y, w0v.y, a0);
          a0 = fmaf(h4.z, w0v.z, a0); a0 = fmaf(h4.w, w0v.w, a0);
          a1 = fmaf(h4.x, w1v.x, a1); a1 = fmaf(h4.y, w1v.y, a1);
          a1 = fmaf(h4.z, w1v.z, a1); a1 = fmaf(h4.w, w1v.w, a1);
        }
      }
      gates_lds[b][jl][g0] = a0;
      gates_lds[b][jl][g0 + 1] = a1;
      __syncthreads();
      if (gp == 0) {
        float vi = gates_lds[b][jl][0], vf = gates_lds[b][jl][1];
        float vg = gates_lds[b][jl][2], vo = gates_lds[b][jl][3];
        float hv = 0.f;
        bool m = (t < len);
        if (m) {
          c = sigm(vf) * c + sigm(vi) * tanhf(vg);
          hv = sigm(vo) * tanhf(c);
        }
        st_f32_ag(&hout[((size_t)(t * 32 + b)) * 512 + j], m ? hv : 0.f);
      }
      ++ep; gbar(p.slots, ep);
    }
  }

  // stage this block's 12 decoder ctx-weight rows (gate g, unit blk*4+rjl) into LDS.
  // Encoder's final gbar (__syncthreads) separates last swu reads from these writes;
  // phase A's gbar separates writes from first D2 reads.
  for (int i = tid; i < 3072; i += 256) {
    int row = i >> 8, f4 = i & 255;
    int g = row >> 2, rjl = row & 3;
    swu[row * 257 + f4] =
        *(const float4*)(p.Wi + ((size_t)(g * 1024 + blk * 4 + rjl)) * 1536 + 512 + f4 * 4);
  }

  // ===== phase A: enc_out assembly + attE = enc_out@Wa[:1024]+ba =====
  {
    for (int r = 0; r < 8; ++r) {
      int fi = blk * 8192 + r * 1024 + tid * 4;
      int b = fi >> 16, s = (fi >> 10) & 63, d = tid * 4;
      float4 v;
      if (d < 512) {
        v = *(const float4*)(p.h_f_out + ((size_t)(s * 32 + b)) * 512 + d);
      } else {
        int len = p.lens[b];
        int rs = (s < len) ? (len - 1 - s) : s;
        v = *(const float4*)(p.h_b_rev + ((size_t)(rs * 32 + b)) * 512 + (d - 512));
      }
      float* ob = p.enc_out + ((size_t)(b * 64 + s)) * 1024 + d;
      st_f32x2_ag(ob, v.x, v.y);        // write-through so decoder XCDs see it;
      st_f32x2_ag(ob + 2, v.z, v.w);    // decoder reads stay L2-cacheable (read-only)
    }
    if (blk < 64) {
      int idx = blk * 256 + tid;
      int h = idx & 7, s = (idx >> 3) & 63, b = idx >> 9;
      int len = p.lens[b];
      int rs = (s < len) ? (len - 1 - s) : s;
      float acc = p.ba[h];
      const float* hf = p.h_f_out + ((size_t)(s * 32 + b)) * 512;
      const float* hb = p.h_b_rev + ((size_t)(rs * 32 + b)) * 512;
      for (int d = 0; d < 512; ++d) acc = fmaf(hf[d], p.Wa[(size_t)d * 8 + h], acc);
      for (int d = 0; d < 512; ++d) acc = fmaf(hb[d], p.Wa[(size_t)(512 + d) * 8 + h], acc);
      st_f32_ag(&p.attE[(size_t)(b * 64 + s) * 8 + h], acc);
    }
    ++ep; gbar(p.slots, ep);
  }

  // ===== decoder: 32 steps, 2 barriers each =====
  for (int t = 0; t < T_DEC_; ++t) {
    float* ctxt = p.ctxbuf + (size_t)t * (32 * 1024);
    float* stt  = p.stbuf  + (size_t)t * (32 * 1024);
    // --- D1: attention + context (blocks 0..31, one per batch) ---
    if (blk < 32) {
      const int b = blk;
      const int len = p.lens[b];
      int h = tid & 7, sl = tid >> 3;
      float qp = 0.f;
      if (t > 0) {
        // stbuf slot t-1: written once at D2(t-1) via agent stores, first read here
        // -> normal cached loads are coherent.
        const float* st = p.stbuf + ((size_t)(t - 1) * 32 + b) * 1024 + sl * 32;
        const float* wa = p.Wa + (size_t)(1024 + sl * 32) * 8 + h;
#pragma unroll
        for (int d4 = 0; d4 < 8; ++d4) {
          float4 sv = *(const float4*)(st + d4 * 4);
          qp = fmaf(sv.x, wa[(d4 * 4 + 0) * 8], qp);
          qp = fmaf(sv.y, wa[(d4 * 4 + 1) * 8], qp);
          qp = fmaf(sv.z, wa[(d4 * 4 + 2) * 8], qp);
          qp = fmaf(sv.w, wa[(d4 * 4 + 3) * 8], qp);
        }
      }
      sh_qp[h][sl] = qp;
      __syncthreads();
      if (tid < 8) {
        float sq = 0.f;
        for (int i = 0; i < 32; ++i) sq += sh_qp[tid][i];
        sh_q[tid] = sq;
      }
      __syncthreads();
      if (tid < 64) {
        int s = tid;
        float sc = -1e9f;
        if (s < len) {
          sc = 0.f;
          const float* ae = p.attE + (size_t)(b * 64 + s) * 8;   // read-only after phase A
#pragma unroll
          for (int hh = 0; hh < 8; ++hh) sc = fmaf(p.va[hh], tanhf(ae[hh] + sh_q[hh]), sc);
        }
        float mx = sc;
        for (int off = 32; off; off >>= 1) mx = fmaxf(mx, __shfl_down(mx, off));
        mx = __shfl(mx, 0);
        float e = expf(sc - mx);
        float sm = e;
        for (int off = 32; off; off >>= 1) sm += __shfl_down(sm, off);
        sm = __shfl(sm, 0);
        sh_al[s] = e / sm;
      }
      __syncthreads();
#pragma unroll
      for (int rr = 0; rr < 4; ++rr) {
        int d = tid + rr * 256;
        float cv = 0.f;
        const float* eo = p.enc_out + (size_t)(b * 64) * 1024 + d;  // read-only, L2-cached
#pragma unroll 8
        for (int s = 0; s < 64; ++s) cv = fmaf(sh_al[s], eo[(size_t)s * 1024], cv);
        st_f32_ag(&ctxt[(size_t)b * 1024 + d], cv);
      }
    }
    ++ep; gbar(p.slots, ep);
    // --- D2: gi_ctx = ctx @ Wi_ctx^T (LDS weights); 256 threads, split-k by 2 ---
    {
      const int b = tid >> 3, jl = (tid >> 1) & 3, kh = tid & 1;
      const float4* wr4 = &swu[(size_t)(0 + jl) * 257 + kh * 128];
      const float4* wz4 = &swu[(size_t)(4 + jl) * 257 + kh * 128];
      const float4* wn4 = &swu[(size_t)(8 + jl) * 257 + kh * 128];
      // ctxbuf slot t: written once in D1(t) via agent stores, first read here
      // -> normal cached loads are coherent (and L2-cacheable per XCD).
      const float4* cb = (const float4*)(ctxt + (size_t)b * 1024 + kh * 512);
      float ar = 0.f, az = 0.f, an = 0.f;
#pragma unroll 8
      for (int kc = 0; kc < 128; ++kc) {
        float4 c4 = cb[kc];
        float4 rv = wr4[kc];
        float4 zv = wz4[kc];
        float4 nv = wn4[kc];
        ar = fmaf(c4.x, rv.x, ar); ar = fmaf(c4.y, rv.y, ar);
        ar = fmaf(c4.z, rv.z, ar); ar = fmaf(c4.w, rv.w, ar);
        az = fmaf(c4.x, zv.x, az); az = fmaf(c4.y, zv.y, az);
        az = fmaf(c4.z, zv.z, az); az = fmaf(c4.w, zv.w, az);
        an = fmaf(c4.x, nv.x, an); an = fmaf(c4.y, nv.y, an);
        an = fmaf(c4.z, nv.z, an); an = fmaf(c4.w, nv.w, an);
      }
      red[b][jl][kh][0] = ar;
      red[b][jl][kh][1] = az;
      red[b][jl][kh][2] = an;
      __syncthreads();
      if (kh == 0) {
        const int j = blk * 4 + jl;
        float arr = red[b][jl][0][0] + red[b][jl][1][0];
        float azz = red[b][jl][0][1] + red[b][jl][1][1];
        float ann = red[b][jl][0][2] + red[b][jl][1][2];
        const float* gpre = p.gi_pre + (size_t)(t * 32 + b) * 3072;
        float gr = arr + gpre[j];
        float gz = azz + gpre[1024 + j];
        float gn = ann + gpre[2048 + j];
        float r = sigm(gr + p.bh[j]);
        float z = sigm(gz + p.bh[1024 + j]);
        float n = tanhf(gn + r * p.bh[2048 + j]);
        float hv = (1.f - z) * n;
        st_f32_ag(&stt[(size_t)b * 1024 + j], hv);
        p.a_cls[(size_t)(t * 32 + b) * 1024 + j] = f2bf(hv);  // cross-kernel: normal store
      }
    }
    ++ep; gbar(p.slots, ep);
  }
}

// ---------------- classifier: bf16 MFMA GEMM + bias + relu ----------------
__global__ __launch_bounds__(256) void cls_kernel(const unsigned short* __restrict__ A_bf,
                                                  const unsigned short* __restrict__ W_bf,
                                                  const float* __restrict__ bc,
                                                  float* __restrict__ out) {
  __shared__ __align__(16) unsigned short s_a[128 * 40];
  __shared__ __align__(16) unsigned short s_b[128 * 40];
  const int tid = threadIdx.x;
  const int n0 = blockIdx.x * 128, m0 = blockIdx.y * 128;
  const int lane = tid & 63, wid = tid >> 6;
  const int wm = (wid & 1) * 64, wn = (wid >> 1) * 64;
  const int lr = lane & 15, quad = lane >> 4;

  f32x4_t acc[4][4];
#pragma unroll
  for (int i = 0; i < 4; ++i)
#pragma unroll
    for (int j = 0; j < 4; ++j) acc[i][j] = (f32x4_t){0.f, 0.f, 0.f, 0.f};

  for (int kc = 0; kc < 1024; kc += 32) {
#pragma unroll
    for (int c = tid; c < 512; c += 256) {
      int r = c >> 2, c4 = c & 3;
      *(uint4*)&s_a[r * 40 + c4 * 8] =
          *(const uint4*)&A_bf[(size_t)(m0 + r) * 1024 + kc + c4 * 8];
      *(uint4*)&s_b[r * 40 + c4 * 8] =
          *(const uint4*)&W_bf[(size_t)(n0 + r) * 1024 + kc + c4 * 8];
    }
    __syncthreads();
    bf16x8_t af[4], bfv[4];
#pragma unroll
    for (int i = 0; i < 4; ++i)
      af[i] = __builtin_bit_cast(bf16x8_t,
               *(const uint4*)&s_a[(wm + i * 16 + lr) * 40 + quad * 8]);
#pragma unroll
    for (int j = 0; j < 4; ++j)
      bfv[j] = __builtin_bit_cast(bf16x8_t,
               *(const uint4*)&s_b[(wn + j * 16 + lr) * 40 + quad * 8]);
#pragma unroll
    for (int i = 0; i < 4; ++i)
#pragma unroll
      for (int j = 0; j < 4; ++j)
        acc[i][j] = __builtin_amdgcn_mfma_f32_16x16x32_bf16(af[i], bfv[j], acc[i][j], 0, 0, 0);
    __syncthreads();
  }

#pragma unroll
  for (int j = 0; j < 4; ++j) {
    int col = n0 + wn + j * 16 + lr;
    float bias = bc[col];
#pragma unroll
    for (int i = 0; i < 4; ++i) {
      int rowb = m0 + wm + i * 16 + quad * 4;
#pragma unroll
      for (int r = 0; r < 4; ++r) {
        int row = rowb + r;
        int tt = row >> 5, bb = row & 31;
        float v = acc[i][j][r] + bias;
        v = v > 0.f ? v : 0.f;
        out[((size_t)(bb * 32 + tt)) * 32000 + col] = v;
      }
    }
  }
}

// ---------------- host launcher ----------------
extern "C" void kernel_launch(void* const* d_in, const int* in_sizes, int n_in,
                              void* d_out, int out_size, void* d_ws, size_t ws_size,
                              hipStream_t stream) {
  const int* enc_in = (const int*)d_in[0];
  const int* enc_len = (const int*)d_in[1];
  const int* dec_in = (const int*)d_in[2];
  const float* emb_f = (const float*)d_in[4];
  const float* emb_e = (const float*)d_in[5];
  const float* W_ih_f = (const float*)d_in[6];
  const float* W_hh_f = (const float*)d_in[7];
  const float* b_ih_f = (const float*)d_in[8];
  const float* b_hh_f = (const float*)d_in[9];
  const float* W_ih_b = (const float*)d_in[10];
  const float* W_hh_b = (const float*)d_in[11];
  const float* b_ih_b = (const float*)d_in[12];
  const float* b_hh_b = (const float*)d_in[13];
  const float* Wa = (const float*)d_in[14];
  const float* ba = (const float*)d_in[15];
  const float* va = (const float*)d_in[16];
  const float* Wi_gru = (const float*)d_in[17];
  const float* bi_gru = (const float*)d_in[19];
  const float* bh_gru = (const float*)d_in[20];
  const float* Wc = (const float*)d_in[21];
  const float* bc = (const float*)d_in[22];
  float* out = (float*)d_out;

  char* ws = (char*)d_ws;
  size_t off = 0;
  auto alloc = [&](size_t bytes) -> char* {
    char* p = ws + off;
    off += (bytes + 255) & ~(size_t)255;
    return p;
  };
  float* xg_f   = (float*)alloc((size_t)64 * 32 * 2048 * 4);
  float* xg_b   = (float*)alloc((size_t)64 * 32 * 2048 * 4);
  float* gi_pre = (float*)alloc((size_t)32 * 32 * 3072 * 4);
  float* h_f_out = (float*)alloc((size_t)64 * 32 * 512 * 4);
  float* h_b_rev = (float*)alloc((size_t)64 * 32 * 512 * 4);
  float* enc_out = (float*)alloc((size_t)32 * 64 * 1024 * 4);
  float* attE    = (float*)alloc((size_t)32 * 64 * 8 * 4);
  float* ctxbuf  = (float*)alloc((size_t)32 * 32 * 1024 * 4);
  float* stbuf   = (float*)alloc((size_t)32 * 32 * 1024 * 4);
  unsigned short* a_cls = (unsigned short*)alloc((size_t)1024 * 1024 * 2);
  unsigned short* wc_bf = (unsigned short*)alloc((size_t)32000 * 1024 * 2);
  unsigned* slots = (unsigned*)alloc(1024);

  hipMemsetAsync(slots, 0, 1024, stream);

  conv_bf16<<<16000, 256, 0, stream>>>(Wc, wc_bf, 4096000);

  gemm_gather<<<dim3(32, 32), 256, 0, stream>>>(emb_f, enc_in, enc_len, W_ih_f, 512,
                                                b_ih_f, b_hh_f, xg_f, 2048, 0);
  gemm_gather<<<dim3(32, 32), 256, 0, stream>>>(emb_f, enc_in, enc_len, W_ih_b, 512,
                                                b_ih_b, b_hh_b, xg_b, 2048, 1);
  gemm_gather<<<dim3(48, 16), 256, 0, stream>>>(emb_e, dec_in, enc_len, Wi_gru, 1536,
                                                bi_gru, nullptr, gi_pre, 3072, 2);

  CoopParams cp;
  cp.lens = enc_len; cp.Wa = Wa; cp.ba = ba; cp.va = va;
  cp.Wi = Wi_gru; cp.bh = bh_gru;
  cp.W_hh_f = W_hh_f; cp.W_hh_b = W_hh_b;
  cp.xg_f = xg_f; cp.xg_b = xg_b; cp.gi_pre = gi_pre;
  cp.h_f_out = h_f_out; cp.h_b_rev = h_b_rev; cp.enc_out = enc_out; cp.attE = attE;
  cp.ctxbuf = ctxbuf; cp.stbuf = stbuf; cp.a_cls = a_cls;
  cp.slots = slots;
  void* args[] = { &cp };
  hipLaunchCooperativeKernel((const void*)coop_kernel, dim3(256), dim3(256), args, 0, stream);

  cls_kernel<<<dim3(250, 8), 256, 0, stream>>>(a_cls, wc_bf, bc, out);
}